// Round 5
// baseline (171.041 us; speedup 1.0000x reference)
//
#include <hip/hip_runtime.h>

#define NFR 500   // n_frames
#define NFQ 320   // n_freq
#define NB  2     // batch
#define NC  6     // n_chan
#define NS  4     // n_src
#define NBK 2     // n_chan - n_src
#define NT  4     // n_taps
#define NDLY 1    // n_delay
#define EPSF 1e-3f
#define TINYF 1e-20f

#define NP   512            // padded frame count (8 x 64 lanes)
#define XPAD 8              // leading zero-pad for shifted X reads
#define XLEN (XPAD + NP)
#define NCH  8              // f-chunks for w partial sums
#define FPC  (NFQ / NCH)    // 40 freqs per chunk

typedef float f2 __attribute__((ext_vector_type(2)));

__device__ __forceinline__ f2 mk2(float r, float i){ f2 t; t.x = r; t.y = i; return t; }
// complex ops on (re,im) pairs — select v_pk_* packed fp32
__device__ __forceinline__ f2 cmul(f2 a, f2 b){ return a.xx*b + a.yy*mk2(-b.y, b.x); }
__device__ __forceinline__ f2 cmulc(f2 a, f2 b){ return b.xx*a + b.yy*mk2(a.y, -a.x); } // a*conj(b)
__device__ __forceinline__ f2 conjc(f2 a){ return mk2(a.x, -a.y); }
__device__ __forceinline__ float cmag2(f2 a){ return a.x*a.x + a.y*a.y; }
__device__ __forceinline__ f2 cinv(f2 a){ float m = a.x*a.x + a.y*a.y; return mk2(a.x/m, -a.y/m); }

__device__ __forceinline__ float wred64(float v){
#pragma unroll
  for (int o = 32; o > 0; o >>= 1) v += __shfl_xor(v, o, 64);
  return v;
}

// ---------------------------------------------------------------------------
// init: C_XX -> J (4x4 diag-loaded solve), W/A = eye, Y = X[:4], Z = J X - X[4:]
// ---------------------------------------------------------------------------
__global__ __launch_bounds__(256) void k_init(
  const float* __restrict__ Xr, const float* __restrict__ Xi,
  f2* __restrict__ Yg, f2* __restrict__ Zg,
  f2* __restrict__ Wg, f2* __restrict__ Jg, f2* __restrict__ Ag)
{
  __shared__ f2 sX[NC][NFR];
  __shared__ f2 sC[NS][NC];
  __shared__ f2 sJl[NBK][NS];

  const int bf = blockIdx.x;
  const int b = bf / NFQ, f = bf % NFQ;
  const int tid = threadIdx.x, wv = tid >> 6, lane = tid & 63;

  for (int c = 0; c < NC; ++c) {
    const size_t base = ((size_t)(b*NC + c)*NFQ + f)*NFR;
    for (int n = tid; n < NFR; n += 256)
      sX[c][n] = mk2(Xr[base+n], Xi[base+n]);
  }
  __syncthreads();

  // C_XX[s][d] = (1/N) sum_n X_s conj(X_d), s<4, d<6
  for (int p = wv; p < NS*NC; p += 4) {
    int s = p / NC, d = p % NC;
    f2 ar2 = mk2(0.f,0.f), ai2 = mk2(0.f,0.f);
    for (int n = lane; n < NFR; n += 64) {
      f2 xs = sX[s][n], xd = sX[d][n];
      ar2 += xs * xd;
      ai2 += xs.yx * mk2(xd.x, -xd.y);
    }
    float ar = wred64(ar2.x + ar2.y), ai = wred64(ai2.x + ai2.y);
    if (lane == 0) sC[s][d] = mk2(ar*(1.f/NFR), ai*(1.f/NFR));
  }
  __syncthreads();

  if (tid == 0) {
    f2 M[NS][NC];
    for (int s = 0; s < NS; ++s)
      for (int d = 0; d < NC; ++d) M[s][d] = sC[s][d];
    float dsum = 0.f;
    for (int s = 0; s < NS; ++s) dsum += sqrtf(cmag2(M[s][s]));
    float load = fmaxf(dsum*1e-5f, 1e-5f);
    for (int s = 0; s < NS; ++s) M[s][s].x += load;
    for (int col = 0; col < NS; ++col) {
      int piv = col; float best = cmag2(M[col][col]);
      for (int r = col+1; r < NS; ++r) { float m = cmag2(M[r][col]); if (m > best){best=m; piv=r;} }
      if (piv != col) for (int k = 0; k < NC; ++k) { f2 t=M[col][k]; M[col][k]=M[piv][k]; M[piv][k]=t; }
      f2 ip = cinv(M[col][col]);
      for (int k = col; k < NC; ++k) M[col][k] = cmul(M[col][k], ip);
      for (int r = 0; r < NS; ++r) if (r != col) {
        f2 fac = M[r][col];
        for (int k = col; k < NC; ++k) M[r][k] -= cmul(fac, M[col][k]);
      }
    }
    for (int k = 0; k < NBK; ++k)
      for (int s = 0; s < NS; ++s) sJl[k][s] = conjc(M[s][NS+k]);
  }
  __syncthreads();

  if (tid < NBK*NS) {
    int k = tid / NS, s = tid % NS;
    Jg[((size_t)(b*NBK+k)*NFQ + f)*NS + s] = sJl[k][s];
  } else if (tid < NBK*NS + NS*NC) {
    int t = tid - NBK*NS; int s = t / NC, d = t % NC;
    Wg[((size_t)(b*NS+s)*NFQ + f)*NC + d] = (s==d) ? mk2(1.f,0.f) : mk2(0.f,0.f);
  } else if (tid < NBK*NS + NS*NC + NS*NS) {
    int t = tid - NBK*NS - NS*NC; int s = t / NS, d = t % NS;
    Ag[((size_t)(b*NS+s)*NFQ + f)*NS + d] = (s==d) ? mk2(1.f,0.f) : mk2(0.f,0.f);
  }
  for (int c = 0; c < NS; ++c) {
    const size_t base = ((size_t)(b*NS + c)*NFQ + f)*NFR;
    for (int n = tid; n < NFR; n += 256) Yg[base+n] = sX[c][n];
  }
  for (int k = 0; k < NBK; ++k) {
    const size_t base = ((size_t)(b*NBK + k)*NFQ + f)*NFR;
    for (int n = tid; n < NFR; n += 256) {
      f2 acc = -sX[NS+k][n];
      for (int s = 0; s < NS; ++s) acc += cmul(sJl[k][s], sX[s][n]);
      Zg[base+n] = acc;
    }
  }
}

// ---------------------------------------------------------------------------
// w partial sums: wacc[ch][bs][n] = sum_{f in chunk ch} |Y[bs,f,n]|^2
// ---------------------------------------------------------------------------
__global__ __launch_bounds__(512) void k_wpart(const f2* __restrict__ Yg,
                                               float* __restrict__ wacc)
{
  const int bs = blockIdx.x / NCH;
  const int ch = blockIdx.x % NCH;
  const int n  = threadIdx.x;
  if (n >= NFR) return;
  const f2* row = Yg + (size_t)bs*NFQ*NFR;
  f2 acc2 = mk2(0.f,0.f);
  for (int ff = 0; ff < FPC; ++ff) {
    f2 y = row[(size_t)(ch*FPC + ff)*NFR + n];
    acc2 += y*y;
  }
  wacc[((size_t)(ch*NB*NS + bs))*NFR + n] = acc2.x + acc2.y;
}

// ---------------------------------------------------------------------------
// one full iss_updates iteration per (b,f) block.
// Serial-depth-reduced: bak rounds use register-persistent v (no scalar phase),
// type2 pair-batched, type3 quad-batched via within-quad Gram correction.
// ---------------------------------------------------------------------------
__global__ __launch_bounds__(256, 3) void k_iter(
  const float* __restrict__ Xr, const float* __restrict__ Xi,
  f2* __restrict__ Yg, f2* __restrict__ Zg,
  f2* __restrict__ Wg, f2* __restrict__ Jg, f2* __restrict__ Ag,
  const float* __restrict__ wacc, float* __restrict__ outR, const int last)
{
  __shared__ f2 sXp[NC][XLEN];   // front/back zero-padded X
  __shared__ f2 sZ[NBK][NP];
  __shared__ f2 sS[NP];
  __shared__ f2 sW[NS][NC];
  __shared__ f2 sJ[NBK][NS];
  __shared__ f2 sA[NS][NS];
  __shared__ f2 sB[NS][2*NS];
  __shared__ f2 sv[NC], sg[NC], sgo[NS], sp[NC];
  __shared__ float sd[NC];
  __shared__ f2 sAv[NS], sgA[NS], sWsrc[NC];

  const int bf = blockIdx.x;
  const int b = bf / NFQ, f = bf % NFQ;
  const int tid = threadIdx.x, wv = tid >> 6, lane = tid & 63;

  f2 yreg[8];   // wave-owned channel wv
  float wreg[8];

  // ---- stage X (zero-padded both ends)
  for (int c = 0; c < NC; ++c) {
    const size_t base = ((size_t)(b*NC + c)*NFQ + f)*NFR;
    for (int j = tid; j < XLEN; j += 256) {
      int n = j - XPAD;
      sXp[c][j] = (n >= 0 && n < NFR) ? mk2(Xr[base+n], Xi[base+n]) : mk2(0.f,0.f);
    }
  }
  // ---- stage Z (zero-padded tail)
  for (int k = 0; k < NBK; ++k) {
    const size_t zb = ((size_t)(b*NBK + k)*NFQ + f)*NFR;
    for (int n = tid; n < NP; n += 256) sZ[k][n] = (n < NFR) ? Zg[zb+n] : mk2(0.f,0.f);
  }
  // ---- Y + w into registers
  {
    const size_t yb = ((size_t)(b*NS + wv)*NFQ + f)*NFR;
    const int bs = b*NS + wv;
#pragma unroll
    for (int i = 0; i < 8; ++i) {
      int n = lane + 64*i;
      if (n < NFR) {
        yreg[i] = Yg[yb+n];
        float a = 0.f;
#pragma unroll
        for (int ch = 0; ch < NCH; ++ch) a += wacc[((size_t)(ch*NB*NS + bs))*NFR + n];
        wreg[i] = 1.0f / fmaxf(a * (1.0f/(float)NFQ), EPSF);
      } else { yreg[i] = mk2(0.f,0.f); wreg[i] = 0.f; }
    }
  }
  if (tid < NS*NC) sW[tid/NC][tid%NC] = Wg[((size_t)(b*NS + tid/NC)*NFQ + f)*NC + tid%NC];
  else if (tid < NS*NC + NBK*NS) { int t=tid-NS*NC; sJ[t/NS][t%NS] = Jg[((size_t)(b*NBK+t/NS)*NFQ+f)*NS + t%NS]; }
  else if (tid < NS*NC + NBK*NS + NS*NS) { int t=tid-NS*NC-NBK*NS; sA[t/NS][t%NS] = Ag[((size_t)(b*NS+t/NS)*NFQ+f)*NS + t%NS]; }
  __syncthreads();

  f2 vloc[NC];   // bak-round v, persists in registers across barriers

  // ================= bak loop (4 barriers/round) =================
  for (int bak = 0; bak < NBK; ++bak) {
    // --- phase S: stage Zs; fold in previous round's A-update (P2)
    for (int n = tid; n < NP; n += 256)
      sS[n] = sZ[bak][n] + sXp[NS+bak][XPAD+n];
    if (bak > 0 && tid < 16) {
      int s = tid >> 2, c = tid & 3;
      f2 v2[NS];
#pragma unroll
      for (int t = 0; t < NS; ++t)
        v2[t] = vloc[t] + cmul(sW[t][NS+0], vloc[NS+0]) + cmul(sW[t][NS+1], vloc[NS+1]);
      f2 den = mk2(1.f,0.f);
#pragma unroll
      for (int cc = 0; cc < NS; ++cc) den -= cmul(v2[cc], sgA[cc]);
      float m2 = cmag2(den) + EPSF;
      f2 mul = mk2(den.x/m2, -den.y/m2);
      sA[s][c] += cmul(sAv[s], cmul(sgA[c], mul));
    }
    __syncthreads();

    // --- phase R: p,d reductions + g + sgo capture
    f2 zs[8];
    {
      f2 pr2 = mk2(0.f,0.f), pi2 = mk2(0.f,0.f), dd2 = mk2(0.f,0.f);
#pragma unroll
      for (int i = 0; i < 8; ++i) {
        zs[i] = sS[lane+64*i];
        f2 wy = wreg[i]*yreg[i];
        pr2 += wy * zs[i];
        pi2 += wy.yx * mk2(zs[i].x, -zs[i].y);
        dd2 += (wreg[i]*zs[i]) * zs[i];
      }
      float pr = wred64(pr2.x+pr2.y), pi = wred64(pi2.x+pi2.y), dd = wred64(dd2.x+dd2.y);
      if (lane == 0) { sp[wv] = mk2(pr*(1.f/NFR), pi*(1.f/NFR)); sd[wv] = dd*(1.f/NFR); }
      if (wv < NBK) {   // channels 4,5 (unweighted, rows = Z)
        f2 qr2 = mk2(0.f,0.f), qi2 = mk2(0.f,0.f), qd2 = mk2(0.f,0.f);
#pragma unroll
        for (int i = 0; i < 8; ++i) {
          f2 y = sZ[wv][lane+64*i];
          qr2 += y * zs[i];
          qi2 += y.yx * mk2(zs[i].x, -zs[i].y);
          qd2 += zs[i]*zs[i];
        }
        float qr = wred64(qr2.x+qr2.y), qi = wred64(qi2.x+qi2.y), qd = wred64(qd2.x+qd2.y);
        if (lane == 0) { sp[NS+wv] = mk2(qr*(1.f/NFR), qi*(1.f/NFR)); sd[NS+wv] = qd*(1.f/NFR); }
      }
    }
    if (tid < NC) {   // g[c] = conj( sum_s J[bak][s] * A2[s][c] )
      int c = tid; f2 acc = mk2(0.f,0.f);
      for (int s = 0; s < NS; ++s) {
        f2 a2;
        if (c < NS) a2 = sA[s][c];
        else {
          a2 = mk2(0.f,0.f);
          for (int k = 0; k < NS; ++k) a2 += cmul(sA[s][k], sW[k][c]);
        }
        acc += cmul(sJ[bak][s], a2);
      }
      sg[c] = conjc(acc);
    } else if (tid >= 8 && tid < 8+NS) {
      sgo[tid-8] = sJ[bak][tid-8];    // snapshot old J[bak]
    }
    __syncthreads();

    // --- phase U: every thread computes ell + v locally; Y/Z updates
    {
      float gdg = 0.f; f2 gdp = mk2(0.f,0.f);
#pragma unroll
      for (int c = 0; c < NC; ++c) {
        f2 gc = sg[c]; float id = 1.0f/(sd[c] + EPSF);
        gdg += cmag2(gc) * id;
        gdp += id * cmulc(sp[c], gc);
      }
      f2 bb = mk2(1.0f - gdp.x, -gdp.y);
      float b1 = cmag2(bb);
      float a = b1*gdg + TINYF;
      float beta = (-b1 + sqrtf(b1*b1 + 4.0f*a)) / (2.0f*a);
      f2 ell = (b1 > EPSF*EPSF) ? (beta*bb) : mk2(1.0f/sqrtf(EPSF + gdg), 0.f);
#pragma unroll
      for (int c = 0; c < NC; ++c)
        vloc[c] = (1.0f/(sd[c] + EPSF)) * (sp[c] - cmul(ell, sg[c]));
    }
    {
      f2 vc = vloc[wv];
#pragma unroll
      for (int i = 0; i < 8; ++i) yreg[i] -= cmul(vc, zs[i]);
      if (wv < NBK) {
        f2 v2c = vloc[NS+wv];
#pragma unroll
        for (int i = 0; i < 8; ++i) sZ[wv][lane+64*i] -= cmul(v2c, zs[i]);
      }
    }
    __syncthreads();

    // --- phase P1: Av, gA, W/J rank-1 updates (disjoint threads, v in regs)
    if (tid < NS) {
      f2 v2[NS];
#pragma unroll
      for (int t = 0; t < NS; ++t)
        v2[t] = vloc[t] + cmul(sW[t][NS+0], vloc[NS+0]) + cmul(sW[t][NS+1], vloc[NS+1]);
      f2 acc = mk2(0.f,0.f);
#pragma unroll
      for (int c = 0; c < NS; ++c) acc += cmul(sA[tid][c], v2[c]);
      sAv[tid] = acc;
    } else if (tid < 2*NS) {
      int c = tid - NS; f2 acc = mk2(0.f,0.f);
#pragma unroll
      for (int s = 0; s < NS; ++s) acc += cmul(sgo[s], sA[s][c]);
      sgA[c] = acc;
    } else if (tid < 2*NS + 16) {
      int idx = tid - 2*NS; int cc = idx >> 2, d = idx & 3;
      sW[cc][d] -= cmul(vloc[cc], sgo[d]);
    } else if (tid < 2*NS + 16 + 8) {
      int idx = tid - 2*NS - 16; int k = idx >> 2, d = idx & 3;
      sJ[k][d] -= cmul(vloc[NS+k], sgo[d]);
    }
    __syncthreads();
  }

  // ================= type1 loop (4 rounds) + deferred mat_up1 ==============
  for (int src = 0; src < NS; ++src) {
    if (wv == src) {
#pragma unroll
      for (int i = 0; i < 8; ++i) sS[lane+64*i] = yreg[i];
    }
    if (tid < NC) sWsrc[tid] = sW[src][tid];
    if (src == 0) {
      if (tid < 16) {     // final P2 of bak loop (uses vloc from bak=1)
        int s = tid >> 2, c = tid & 3;
        f2 v2[NS];
#pragma unroll
        for (int t = 0; t < NS; ++t)
          v2[t] = vloc[t] + cmul(sW[t][NS+0], vloc[NS+0]) + cmul(sW[t][NS+1], vloc[NS+1]);
        f2 den = mk2(1.f,0.f);
#pragma unroll
        for (int cc = 0; cc < NS; ++cc) den -= cmul(v2[cc], sgA[cc]);
        float m2 = cmag2(den) + EPSF;
        f2 mul = mk2(den.x/m2, -den.y/m2);
        sA[s][c] += cmul(sAv[s], cmul(sgA[c], mul));
      }
    } else if (tid >= 8 && tid < 8+NS) {   // mat_up1 for previous src
      int r = tid - 8, prev = src - 1;
      f2 acc = mk2(0.f,0.f);
#pragma unroll
      for (int c = 0; c < NS; ++c) acc += cmul(sA[r][c], sv[c]);
      float den = 1.0f - sv[prev].x + EPSF;
      sA[r][prev] += (1.0f/den) * acc;
    }
    __syncthreads();

    {
      f2 ys[8];
      f2 nr2 = mk2(0.f,0.f), ni2 = mk2(0.f,0.f), dd2 = mk2(0.f,0.f);
#pragma unroll
      for (int i = 0; i < 8; ++i) {
        ys[i] = sS[lane+64*i];
        f2 wy = wreg[i]*yreg[i];
        nr2 += wy * ys[i];
        ni2 += wy.yx * mk2(ys[i].x, -ys[i].y);
        dd2 += (wreg[i]*ys[i]) * ys[i];
      }
      float nr = wred64(nr2.x+nr2.y)*(1.f/NFR);
      float ni = wred64(ni2.x+ni2.y)*(1.f/NFR);
      float dd = wred64(dd2.x+dd2.y)*(1.f/NFR);
      f2 vc;
      if (wv == src) vc = mk2(1.0f - 1.0f/sqrtf(fmaxf(dd, EPSF)), 0.f);
      else           vc = (1.0f/fmaxf(dd, EPSF)) * mk2(nr, ni);
      if (lane == 0) sv[wv] = vc;
#pragma unroll
      for (int i = 0; i < 8; ++i) yreg[i] -= cmul(vc, ys[i]);
      if (lane < NC) sW[wv][lane] -= cmul(vc, sWsrc[lane]);
    }
    __syncthreads();
  }
  // (mat_up1 for src=3 is dead: A is overwritten by the Binv inverse below)

  // ================= type2: pair-batched (barrier-free, Z rows fixed) ======
  {
    f2 pr0=mk2(0,0), pi0=mk2(0,0), dd0=mk2(0,0);
    f2 pr1=mk2(0,0), pi1=mk2(0,0), dd1=mk2(0,0);
    f2 crr=mk2(0,0), cri=mk2(0,0);
    f2 z0c[8], z1c[8];
#pragma unroll
    for (int i = 0; i < 8; ++i) {
      f2 z0 = sZ[0][lane+64*i], z1 = sZ[1][lane+64*i];
      z0c[i] = z0; z1c[i] = z1;
      f2 wy = wreg[i]*yreg[i];
      f2 wz0 = wreg[i]*z0;
      pr0 += wy * z0;  pi0 += wy.yx * mk2(z0.x, -z0.y);  dd0 += wz0 * z0;
      pr1 += wy * z1;  pi1 += wy.yx * mk2(z1.x, -z1.y);  dd1 += (wreg[i]*z1) * z1;
      crr += wz0 * z1; cri += wz0.yx * mk2(z1.x, -z1.y);   // Rz = sum w z0 conj(z1)
    }
    float P0r = wred64(pr0.x+pr0.y), P0i = wred64(pi0.x+pi0.y), D0 = wred64(dd0.x+dd0.y);
    float P1r = wred64(pr1.x+pr1.y), P1i = wred64(pi1.x+pi1.y), D1 = wred64(dd1.x+dd1.y);
    float Rr  = wred64(crr.x+crr.y), Ri  = wred64(cri.x+cri.y);
    f2 v0 = (1.0f/fmaxf(D0, EPSF)) * mk2(P0r, P0i);
    f2 P1c = mk2(P1r, P1i) - cmul(v0, mk2(Rr, Ri));
    f2 v1 = (1.0f/fmaxf(D1, EPSF)) * P1c;
#pragma unroll
    for (int i = 0; i < 8; ++i) yreg[i] -= cmul(v0, z0c[i]) + cmul(v1, z1c[i]);
    if (lane < NS) sW[wv][lane] -= cmul(v0, sJ[0][lane]) + cmul(v1, sJ[1][lane]);
    else if (lane == NS)   sW[wv][NS+0] += v0;
    else if (lane == NS+1) sW[wv][NS+1] += v1;
  }
  __syncthreads();

  // ================= Binv -> inv (GJ on lane 0 of wave 0; overlaps type3) ===
  if (tid < 16) {
    int s = tid >> 2, d = tid & 3;
    f2 acc = sW[s][d];
    acc += cmul(sW[s][NS+0], sJ[0][d]);
    acc += cmul(sW[s][NS+1], sJ[1][d]);
    sB[s][d] = acc;
    sB[s][NS+d] = (s==d) ? mk2(1.f,0.f) : mk2(0.f,0.f);
  }
  __syncthreads();
  if (tid == 0) {
    for (int col = 0; col < NS; ++col) {
      int piv = col; float best = cmag2(sB[col][col]);
      for (int r = col+1; r < NS; ++r) { float m = cmag2(sB[r][col]); if (m > best) { best = m; piv = r; } }
      if (piv != col) for (int k = 0; k < 2*NS; ++k) { f2 t = sB[col][k]; sB[col][k] = sB[piv][k]; sB[piv][k] = t; }
      f2 ip = cinv(sB[col][col]);
      for (int k = 0; k < 2*NS; ++k) sB[col][k] = cmul(sB[col][k], ip);
      for (int r = 0; r < NS; ++r) if (r != col) {
        f2 fac = sB[r][col];
        for (int k = 0; k < 2*NS; ++k) sB[r][k] -= cmul(fac, sB[col][k]);
      }
    }
  }

  // ================= type3: quad-batched over taps (barrier-free) ==========
  {
#pragma unroll 1
    for (int src = 0; src < NC; ++src) {
      const f2* __restrict__ xrow = &sXp[src][0];
      const int base0 = XPAD - NDLY + lane;     // tap t -> base0 - t (+64 i)
      f2 pr[NT], pi[NT], ddv[NT], rr[6], ri[6];
#pragma unroll
      for (int t = 0; t < NT; ++t) { pr[t]=mk2(0,0); pi[t]=mk2(0,0); ddv[t]=mk2(0,0); }
#pragma unroll
      for (int q = 0; q < 6; ++q) { rr[q]=mk2(0,0); ri[q]=mk2(0,0); }
#pragma unroll
      for (int i = 0; i < 8; ++i) {
        const int p0 = base0 + 64*i;
        f2 xs[NT], nx[NT], wx[NT];
#pragma unroll
        for (int t = 0; t < NT; ++t) {
          xs[t] = xrow[p0 - t];
          nx[t] = mk2(xs[t].x, -xs[t].y);
          wx[t] = wreg[i]*xs[t];
        }
        f2 wy = wreg[i]*yreg[i];
#pragma unroll
        for (int t = 0; t < NT; ++t) {
          pr[t] += wy * xs[t];
          pi[t] += wy.yx * nx[t];
          ddv[t] += wx[t] * xs[t];
        }
        int q = 0;
#pragma unroll
        for (int t = 0; t < NT; ++t)
#pragma unroll
          for (int u = t+1; u < NT; ++u, ++q) {
            rr[q] += wx[t] * xs[u];
            ri[q] += wx[t].yx * nx[u];
          }
      }
      f2 P[NT]; float D[NT]; f2 R[6];
#pragma unroll
      for (int t = 0; t < NT; ++t) {
        P[t] = mk2(wred64(pr[t].x+pr[t].y), wred64(pi[t].x+pi[t].y));
        D[t] = wred64(ddv[t].x+ddv[t].y);
      }
#pragma unroll
      for (int q = 0; q < 6; ++q) R[q] = mk2(wred64(rr[q].x+rr[q].y), wred64(ri[q].x+ri[q].y));
      // sequential recurrence on scalars (exact ISS ordering)
      f2 v[NT];
      v[0] = (1.0f/fmaxf(D[0], EPSF)) * P[0];
      P[1] -= cmul(v[0], R[0]);
      v[1] = (1.0f/fmaxf(D[1], EPSF)) * P[1];
      P[2] -= cmul(v[0], R[1]) + cmul(v[1], R[3]);
      v[2] = (1.0f/fmaxf(D[2], EPSF)) * P[2];
      P[3] -= cmul(v[0], R[2]) + cmul(v[1], R[4]) + cmul(v[2], R[5]);
      v[3] = (1.0f/fmaxf(D[3], EPSF)) * P[3];
      // one combined update
#pragma unroll
      for (int i = 0; i < 8; ++i) {
        const int p0 = base0 + 64*i;
        f2 acc = yreg[i];
#pragma unroll
        for (int t = 0; t < NT; ++t) acc -= cmul(v[t], xrow[p0 - t]);
        yreg[i] = acc;
      }
    }
  }

  // ================= epilogue =================
  {
    const size_t yb = ((size_t)(b*NS + wv)*NFQ + f)*NFR;
    if (last) {
#pragma unroll
      for (int i = 0; i < 8; ++i) { int n = lane+64*i; if (n < NFR) outR[yb+n] = yreg[i].x; }
    } else {
#pragma unroll
      for (int i = 0; i < 8; ++i) { int n = lane+64*i; if (n < NFR) Yg[yb+n] = yreg[i]; }
    }
  }
  if (!last) {
    __syncthreads();   // sB (GJ), sW/sJ cross-wave reads below
    for (int k = 0; k < NBK; ++k) {
      const size_t zb = ((size_t)(b*NBK+k)*NFQ + f)*NFR;
      for (int n = tid; n < NFR; n += 256) Zg[zb+n] = sZ[k][n];
    }
    if (tid < NS*NC) Wg[((size_t)(b*NS + tid/NC)*NFQ + f)*NC + tid%NC] = sW[tid/NC][tid%NC];
    else if (tid < NS*NC + NBK*NS) { int t = tid - NS*NC; Jg[((size_t)(b*NBK + t/NS)*NFQ + f)*NS + t%NS] = sJ[t/NS][t%NS]; }
    else if (tid < NS*NC + NBK*NS + NS*NS) { int t = tid - NS*NC - NBK*NS; Ag[((size_t)(b*NS + t/NS)*NFQ + f)*NS + t%NS] = sB[t/NS][NS + t%NS]; }
  }
}

// ---------------------------------------------------------------------------
extern "C" void kernel_launch(void* const* d_in, const int* in_sizes, int n_in,
                              void* d_out, int out_size, void* d_ws, size_t ws_size,
                              hipStream_t stream)
{
  (void)in_sizes; (void)n_in; (void)out_size; (void)ws_size;
  const float* Xr = (const float*)d_in[0];
  const float* Xi = (const float*)d_in[1];
  float* outR = (float*)d_out;   // d_out = re(Y), float32, (2,4,320,500)

  char* ws = (char*)d_ws;
  size_t off = 0;
  f2* Yg = (f2*)(ws + off); off += (size_t)NB*NS*NFQ*NFR*sizeof(f2);   // 10,240,000
  f2* Zg = (f2*)(ws + off); off += (size_t)NB*NBK*NFQ*NFR*sizeof(f2);  //  5,120,000
  f2* Wg = (f2*)(ws + off); off += (size_t)NB*NS*NFQ*NC*sizeof(f2);    //    122,880
  f2* Jg = (f2*)(ws + off); off += (size_t)NB*NBK*NFQ*NS*sizeof(f2);   //     40,960
  f2* Ag = (f2*)(ws + off); off += (size_t)NB*NS*NFQ*NS*sizeof(f2);    //     81,920
  float* wacc = (float*)(ws + off); off += (size_t)NCH*NB*NS*NFR*sizeof(float); // 128,000

  k_init<<<NB*NFQ, 256, 0, stream>>>(Xr, Xi, Yg, Zg, Wg, Jg, Ag);
  for (int it = 0; it < 2; ++it) {
    k_wpart<<<NB*NS*NCH, 512, 0, stream>>>(Yg, wacc);
    k_iter<<<NB*NFQ, 256, 0, stream>>>(Xr, Xi, Yg, Zg, Wg, Jg, Ag, wacc, outR, it == 1);
  }
}

// Round 6
// 136.386 us; speedup vs baseline: 1.2541x; 1.2541x over previous
//
#include <hip/hip_runtime.h>

#define NFR 500   // n_frames
#define NFQ 320   // n_freq
#define NB  2     // batch
#define NC  6     // n_chan
#define NS  4     // n_src
#define NBK 2     // n_chan - n_src
#define NT  4     // n_taps
#define NDLY 1    // n_delay
#define EPSF 1e-3f
#define TINYF 1e-20f

#define NP   512            // padded frame count (8 x 64 lanes)
#define XPAD 8              // leading zero-pad for shifted X reads
#define XLEN (XPAD + NP)
#define NCH  8              // f-chunks for w partial sums
#define FPC  (NFQ / NCH)    // 40 freqs per chunk

typedef float f2 __attribute__((ext_vector_type(2)));

__device__ __forceinline__ f2 mk2(float r, float i){ f2 t; t.x = r; t.y = i; return t; }
// complex ops on (re,im) pairs — select v_pk_* packed fp32
__device__ __forceinline__ f2 cmul(f2 a, f2 b){ return a.xx*b + a.yy*mk2(-b.y, b.x); }
__device__ __forceinline__ f2 cmulc(f2 a, f2 b){ return b.xx*a + b.yy*mk2(a.y, -a.x); } // a*conj(b)
__device__ __forceinline__ f2 conjc(f2 a){ return mk2(a.x, -a.y); }
__device__ __forceinline__ float cmag2(f2 a){ return a.x*a.x + a.y*a.y; }
__device__ __forceinline__ f2 cinv(f2 a){ float m = a.x*a.x + a.y*a.y; return mk2(a.x/m, -a.y/m); }

// wave64 sum-reduce via DPP (VALU latency) instead of ds_swizzle butterflies.
// row_shr 1/2/4/8 -> each row's lane15 has row sum; row_bcast15/31 cascade;
// lane 63 holds the total; readlane broadcasts it uniformly.
#define DPPF(x, ctrl) __int_as_float(__builtin_amdgcn_mov_dpp(__float_as_int(x), (ctrl), 0xF, 0xF, true))
__device__ __forceinline__ float wred64(float x){
  x += DPPF(x, 0x111);   // row_shr:1
  x += DPPF(x, 0x112);   // row_shr:2
  x += DPPF(x, 0x114);   // row_shr:4
  x += DPPF(x, 0x118);   // row_shr:8
  x += DPPF(x, 0x142);   // row_bcast:15
  x += DPPF(x, 0x143);   // row_bcast:31
  return __int_as_float(__builtin_amdgcn_readlane(__float_as_int(x), 63));
}

// ---------------------------------------------------------------------------
// init: C_XX -> J (4x4 diag-loaded solve), W/A = eye, Y = X[:4], Z = J X - X[4:]
// ---------------------------------------------------------------------------
__global__ __launch_bounds__(256) void k_init(
  const float* __restrict__ Xr, const float* __restrict__ Xi,
  f2* __restrict__ Yg, f2* __restrict__ Zg,
  f2* __restrict__ Wg, f2* __restrict__ Jg, f2* __restrict__ Ag)
{
  __shared__ f2 sX[NC][NFR];
  __shared__ f2 sC[NS][NC];
  __shared__ f2 sJl[NBK][NS];

  const int bf = blockIdx.x;
  const int b = bf / NFQ, f = bf % NFQ;
  const int tid = threadIdx.x, wv = tid >> 6, lane = tid & 63;

  for (int c = 0; c < NC; ++c) {
    const size_t base = ((size_t)(b*NC + c)*NFQ + f)*NFR;
    for (int n = tid; n < NFR; n += 256)
      sX[c][n] = mk2(Xr[base+n], Xi[base+n]);
  }
  __syncthreads();

  // C_XX[s][d] = (1/N) sum_n X_s conj(X_d), s<4, d<6
  for (int p = wv; p < NS*NC; p += 4) {
    int s = p / NC, d = p % NC;
    f2 ar2 = mk2(0.f,0.f), ai2 = mk2(0.f,0.f);
    for (int n = lane; n < NFR; n += 64) {
      f2 xs = sX[s][n], xd = sX[d][n];
      ar2 += xs * xd;
      ai2 += xs.yx * mk2(xd.x, -xd.y);
    }
    float ar = wred64(ar2.x + ar2.y), ai = wred64(ai2.x + ai2.y);
    if (lane == 0) sC[s][d] = mk2(ar*(1.f/NFR), ai*(1.f/NFR));
  }
  __syncthreads();

  if (tid == 0) {
    f2 M[NS][NC];
    for (int s = 0; s < NS; ++s)
      for (int d = 0; d < NC; ++d) M[s][d] = sC[s][d];
    float dsum = 0.f;
    for (int s = 0; s < NS; ++s) dsum += sqrtf(cmag2(M[s][s]));
    float load = fmaxf(dsum*1e-5f, 1e-5f);
    for (int s = 0; s < NS; ++s) M[s][s].x += load;
    for (int col = 0; col < NS; ++col) {
      int piv = col; float best = cmag2(M[col][col]);
      for (int r = col+1; r < NS; ++r) { float m = cmag2(M[r][col]); if (m > best){best=m; piv=r;} }
      if (piv != col) for (int k = 0; k < NC; ++k) { f2 t=M[col][k]; M[col][k]=M[piv][k]; M[piv][k]=t; }
      f2 ip = cinv(M[col][col]);
      for (int k = col; k < NC; ++k) M[col][k] = cmul(M[col][k], ip);
      for (int r = 0; r < NS; ++r) if (r != col) {
        f2 fac = M[r][col];
        for (int k = col; k < NC; ++k) M[r][k] -= cmul(fac, M[col][k]);
      }
    }
    for (int k = 0; k < NBK; ++k)
      for (int s = 0; s < NS; ++s) sJl[k][s] = conjc(M[s][NS+k]);
  }
  __syncthreads();

  if (tid < NBK*NS) {
    int k = tid / NS, s = tid % NS;
    Jg[((size_t)(b*NBK+k)*NFQ + f)*NS + s] = sJl[k][s];
  } else if (tid < NBK*NS + NS*NC) {
    int t = tid - NBK*NS; int s = t / NC, d = t % NC;
    Wg[((size_t)(b*NS+s)*NFQ + f)*NC + d] = (s==d) ? mk2(1.f,0.f) : mk2(0.f,0.f);
  } else if (tid < NBK*NS + NS*NC + NS*NS) {
    int t = tid - NBK*NS - NS*NC; int s = t / NS, d = t % NS;
    Ag[((size_t)(b*NS+s)*NFQ + f)*NS + d] = (s==d) ? mk2(1.f,0.f) : mk2(0.f,0.f);
  }
  for (int c = 0; c < NS; ++c) {
    const size_t base = ((size_t)(b*NS + c)*NFQ + f)*NFR;
    for (int n = tid; n < NFR; n += 256) Yg[base+n] = sX[c][n];
  }
  for (int k = 0; k < NBK; ++k) {
    const size_t base = ((size_t)(b*NBK + k)*NFQ + f)*NFR;
    for (int n = tid; n < NFR; n += 256) {
      f2 acc = -sX[NS+k][n];
      for (int s = 0; s < NS; ++s) acc += cmul(sJl[k][s], sX[s][n]);
      Zg[base+n] = acc;
    }
  }
}

// ---------------------------------------------------------------------------
// w partial sums: wacc[ch][bs][n] = sum_{f in chunk ch} |Y[bs,f,n]|^2
// ---------------------------------------------------------------------------
__global__ __launch_bounds__(512) void k_wpart(const f2* __restrict__ Yg,
                                               float* __restrict__ wacc)
{
  const int bs = blockIdx.x / NCH;
  const int ch = blockIdx.x % NCH;
  const int n  = threadIdx.x;
  if (n >= NFR) return;
  const f2* row = Yg + (size_t)bs*NFQ*NFR;
  f2 acc2 = mk2(0.f,0.f);
  for (int ff = 0; ff < FPC; ++ff) {
    f2 y = row[(size_t)(ch*FPC + ff)*NFR + n];
    acc2 += y*y;
  }
  wacc[((size_t)(ch*NB*NS + bs))*NFR + n] = acc2.x + acc2.y;
}

// ---------------------------------------------------------------------------
// one full iss_updates iteration per (b,f) block. Y,w in registers (wave-owned
// channel); X zero-padded in LDS; packed-fp32 math; DPP reductions; H dead.
// bak loop: 4 barriers/round, v computed redundantly per thread (registers).
// type2 pair-batched; type3 sequential (round-4 form).
// ---------------------------------------------------------------------------
__global__ __launch_bounds__(256, 4) void k_iter(
  const float* __restrict__ Xr, const float* __restrict__ Xi,
  f2* __restrict__ Yg, f2* __restrict__ Zg,
  f2* __restrict__ Wg, f2* __restrict__ Jg, f2* __restrict__ Ag,
  const float* __restrict__ wacc, float* __restrict__ outR, const int last)
{
  __shared__ f2 sXp[NC][XLEN];   // front/back zero-padded X
  __shared__ f2 sZ[NBK][NP];
  __shared__ f2 sS[NP];
  __shared__ f2 sW[NS][NC];
  __shared__ f2 sJ[NBK][NS];
  __shared__ f2 sA[NS][NS];
  __shared__ f2 sB[NS][2*NS];
  __shared__ f2 sv[NC], sg[NC], sgo[NS], sp[NC];
  __shared__ float sd[NC];
  __shared__ f2 sAv[NS], sgA[NS], sWsrc[NC];

  const int bf = blockIdx.x;
  const int b = bf / NFQ, f = bf % NFQ;
  const int tid = threadIdx.x, wv = tid >> 6, lane = tid & 63;

  f2 yreg[8];   // wave-owned channel wv
  float wreg[8];

  // ---- stage X (zero-padded both ends)
  for (int c = 0; c < NC; ++c) {
    const size_t base = ((size_t)(b*NC + c)*NFQ + f)*NFR;
    for (int j = tid; j < XLEN; j += 256) {
      int n = j - XPAD;
      sXp[c][j] = (n >= 0 && n < NFR) ? mk2(Xr[base+n], Xi[base+n]) : mk2(0.f,0.f);
    }
  }
  // ---- stage Z (zero-padded tail)
  for (int k = 0; k < NBK; ++k) {
    const size_t zb = ((size_t)(b*NBK + k)*NFQ + f)*NFR;
    for (int n = tid; n < NP; n += 256) sZ[k][n] = (n < NFR) ? Zg[zb+n] : mk2(0.f,0.f);
  }
  // ---- Y + w into registers
  {
    const size_t yb = ((size_t)(b*NS + wv)*NFQ + f)*NFR;
    const int bs = b*NS + wv;
#pragma unroll
    for (int i = 0; i < 8; ++i) {
      int n = lane + 64*i;
      if (n < NFR) {
        yreg[i] = Yg[yb+n];
        float a = 0.f;
#pragma unroll
        for (int ch = 0; ch < NCH; ++ch) a += wacc[((size_t)(ch*NB*NS + bs))*NFR + n];
        wreg[i] = 1.0f / fmaxf(a * (1.0f/(float)NFQ), EPSF);
      } else { yreg[i] = mk2(0.f,0.f); wreg[i] = 0.f; }
    }
  }
  if (tid < NS*NC) sW[tid/NC][tid%NC] = Wg[((size_t)(b*NS + tid/NC)*NFQ + f)*NC + tid%NC];
  else if (tid < NS*NC + NBK*NS) { int t=tid-NS*NC; sJ[t/NS][t%NS] = Jg[((size_t)(b*NBK+t/NS)*NFQ+f)*NS + t%NS]; }
  else if (tid < NS*NC + NBK*NS + NS*NS) { int t=tid-NS*NC-NBK*NS; sA[t/NS][t%NS] = Ag[((size_t)(b*NS+t/NS)*NFQ+f)*NS + t%NS]; }
  __syncthreads();

  f2 vloc[NC];   // bak-round v, persists in registers across barriers

  // ================= bak loop (4 barriers/round) =================
  for (int bak = 0; bak < NBK; ++bak) {
    // --- phase S: stage Zs; fold in previous round's A-update (P2)
    for (int n = tid; n < NP; n += 256)
      sS[n] = sZ[bak][n] + sXp[NS+bak][XPAD+n];
    if (bak > 0 && tid < 16) {
      int s = tid >> 2, c = tid & 3;
      f2 v2[NS];
#pragma unroll
      for (int t = 0; t < NS; ++t)
        v2[t] = vloc[t] + cmul(sW[t][NS+0], vloc[NS+0]) + cmul(sW[t][NS+1], vloc[NS+1]);
      f2 den = mk2(1.f,0.f);
#pragma unroll
      for (int cc = 0; cc < NS; ++cc) den -= cmul(v2[cc], sgA[cc]);
      float m2 = cmag2(den) + EPSF;
      f2 mul = mk2(den.x/m2, -den.y/m2);
      sA[s][c] += cmul(sAv[s], cmul(sgA[c], mul));
    }
    __syncthreads();

    // --- phase R: p,d reductions + g + sgo capture
    f2 zs[8];
    {
      f2 pr2 = mk2(0.f,0.f), pi2 = mk2(0.f,0.f), dd2 = mk2(0.f,0.f);
#pragma unroll
      for (int i = 0; i < 8; ++i) {
        zs[i] = sS[lane+64*i];
        f2 wy = wreg[i]*yreg[i];
        pr2 += wy * zs[i];
        pi2 += wy.yx * mk2(zs[i].x, -zs[i].y);
        dd2 += (wreg[i]*zs[i]) * zs[i];
      }
      float pr = wred64(pr2.x+pr2.y), pi = wred64(pi2.x+pi2.y), dd = wred64(dd2.x+dd2.y);
      if (lane == 0) { sp[wv] = mk2(pr*(1.f/NFR), pi*(1.f/NFR)); sd[wv] = dd*(1.f/NFR); }
      if (wv < NBK) {   // channels 4,5 (unweighted, rows = Z)
        f2 qr2 = mk2(0.f,0.f), qi2 = mk2(0.f,0.f), qd2 = mk2(0.f,0.f);
#pragma unroll
        for (int i = 0; i < 8; ++i) {
          f2 y = sZ[wv][lane+64*i];
          qr2 += y * zs[i];
          qi2 += y.yx * mk2(zs[i].x, -zs[i].y);
          qd2 += zs[i]*zs[i];
        }
        float qr = wred64(qr2.x+qr2.y), qi = wred64(qi2.x+qi2.y), qd = wred64(qd2.x+qd2.y);
        if (lane == 0) { sp[NS+wv] = mk2(qr*(1.f/NFR), qi*(1.f/NFR)); sd[NS+wv] = qd*(1.f/NFR); }
      }
    }
    if (tid < NC) {   // g[c] = conj( sum_s J[bak][s] * A2[s][c] )
      int c = tid; f2 acc = mk2(0.f,0.f);
      for (int s = 0; s < NS; ++s) {
        f2 a2;
        if (c < NS) a2 = sA[s][c];
        else {
          a2 = mk2(0.f,0.f);
          for (int k = 0; k < NS; ++k) a2 += cmul(sA[s][k], sW[k][c]);
        }
        acc += cmul(sJ[bak][s], a2);
      }
      sg[c] = conjc(acc);
    } else if (tid >= 8 && tid < 8+NS) {
      sgo[tid-8] = sJ[bak][tid-8];    // snapshot old J[bak]
    }
    __syncthreads();

    // --- phase U: every thread computes ell + v locally; Y/Z updates
    {
      float gdg = 0.f; f2 gdp = mk2(0.f,0.f);
#pragma unroll
      for (int c = 0; c < NC; ++c) {
        f2 gc = sg[c]; float id = 1.0f/(sd[c] + EPSF);
        gdg += cmag2(gc) * id;
        gdp += id * cmulc(sp[c], gc);
      }
      f2 bb = mk2(1.0f - gdp.x, -gdp.y);
      float b1 = cmag2(bb);
      float a = b1*gdg + TINYF;
      float beta = (-b1 + sqrtf(b1*b1 + 4.0f*a)) / (2.0f*a);
      f2 ell = (b1 > EPSF*EPSF) ? (beta*bb) : mk2(1.0f/sqrtf(EPSF + gdg), 0.f);
#pragma unroll
      for (int c = 0; c < NC; ++c)
        vloc[c] = (1.0f/(sd[c] + EPSF)) * (sp[c] - cmul(ell, sg[c]));
    }
    {
      f2 vc = vloc[wv];
#pragma unroll
      for (int i = 0; i < 8; ++i) yreg[i] -= cmul(vc, zs[i]);
      if (wv < NBK) {
        f2 v2c = vloc[NS+wv];
#pragma unroll
        for (int i = 0; i < 8; ++i) sZ[wv][lane+64*i] -= cmul(v2c, zs[i]);
      }
    }
    __syncthreads();

    // --- phase P1: Av, gA, W/J rank-1 updates (disjoint threads, v in regs)
    if (tid < NS) {
      f2 v2[NS];
#pragma unroll
      for (int t = 0; t < NS; ++t)
        v2[t] = vloc[t] + cmul(sW[t][NS+0], vloc[NS+0]) + cmul(sW[t][NS+1], vloc[NS+1]);
      f2 acc = mk2(0.f,0.f);
#pragma unroll
      for (int c = 0; c < NS; ++c) acc += cmul(sA[tid][c], v2[c]);
      sAv[tid] = acc;
    } else if (tid < 2*NS) {
      int c = tid - NS; f2 acc = mk2(0.f,0.f);
#pragma unroll
      for (int s = 0; s < NS; ++s) acc += cmul(sgo[s], sA[s][c]);
      sgA[c] = acc;
    } else if (tid < 2*NS + 16) {
      int idx = tid - 2*NS; int cc = idx >> 2, d = idx & 3;
      sW[cc][d] -= cmul(vloc[cc], sgo[d]);
    } else if (tid < 2*NS + 16 + 8) {
      int idx = tid - 2*NS - 16; int k = idx >> 2, d = idx & 3;
      sJ[k][d] -= cmul(vloc[NS+k], sgo[d]);
    }
    __syncthreads();
  }

  // ================= type1 loop (4 rounds) + deferred mat_up1 ==============
  for (int src = 0; src < NS; ++src) {
    if (wv == src) {
#pragma unroll
      for (int i = 0; i < 8; ++i) sS[lane+64*i] = yreg[i];
    }
    if (tid < NC) sWsrc[tid] = sW[src][tid];
    if (src == 0) {
      if (tid < 16) {     // final P2 of bak loop (uses vloc from bak=1)
        int s = tid >> 2, c = tid & 3;
        f2 v2[NS];
#pragma unroll
        for (int t = 0; t < NS; ++t)
          v2[t] = vloc[t] + cmul(sW[t][NS+0], vloc[NS+0]) + cmul(sW[t][NS+1], vloc[NS+1]);
        f2 den = mk2(1.f,0.f);
#pragma unroll
        for (int cc = 0; cc < NS; ++cc) den -= cmul(v2[cc], sgA[cc]);
        float m2 = cmag2(den) + EPSF;
        f2 mul = mk2(den.x/m2, -den.y/m2);
        sA[s][c] += cmul(sAv[s], cmul(sgA[c], mul));
      }
    } else if (tid >= 8 && tid < 8+NS) {   // mat_up1 for previous src
      int r = tid - 8, prev = src - 1;
      f2 acc = mk2(0.f,0.f);
#pragma unroll
      for (int c = 0; c < NS; ++c) acc += cmul(sA[r][c], sv[c]);
      float den = 1.0f - sv[prev].x + EPSF;
      sA[r][prev] += (1.0f/den) * acc;
    }
    __syncthreads();

    {
      f2 ys[8];
      f2 nr2 = mk2(0.f,0.f), ni2 = mk2(0.f,0.f), dd2 = mk2(0.f,0.f);
#pragma unroll
      for (int i = 0; i < 8; ++i) {
        ys[i] = sS[lane+64*i];
        f2 wy = wreg[i]*yreg[i];
        nr2 += wy * ys[i];
        ni2 += wy.yx * mk2(ys[i].x, -ys[i].y);
        dd2 += (wreg[i]*ys[i]) * ys[i];
      }
      float nr = wred64(nr2.x+nr2.y)*(1.f/NFR);
      float ni = wred64(ni2.x+ni2.y)*(1.f/NFR);
      float dd = wred64(dd2.x+dd2.y)*(1.f/NFR);
      f2 vc;
      if (wv == src) vc = mk2(1.0f - 1.0f/sqrtf(fmaxf(dd, EPSF)), 0.f);
      else           vc = (1.0f/fmaxf(dd, EPSF)) * mk2(nr, ni);
      if (lane == 0) sv[wv] = vc;
#pragma unroll
      for (int i = 0; i < 8; ++i) yreg[i] -= cmul(vc, ys[i]);
      if (lane < NC) sW[wv][lane] -= cmul(vc, sWsrc[lane]);
    }
    __syncthreads();
  }
  // (mat_up1 for src=3 is dead: A is overwritten by the Binv inverse below)

  // ================= type2: pair-batched (barrier-free, Z rows fixed) ======
  {
    f2 pr0=mk2(0,0), pi0=mk2(0,0), dd0=mk2(0,0);
    f2 pr1=mk2(0,0), pi1=mk2(0,0), dd1=mk2(0,0);
    f2 crr=mk2(0,0), cri=mk2(0,0);
    f2 z0c[8], z1c[8];
#pragma unroll
    for (int i = 0; i < 8; ++i) {
      f2 z0 = sZ[0][lane+64*i], z1 = sZ[1][lane+64*i];
      z0c[i] = z0; z1c[i] = z1;
      f2 wy = wreg[i]*yreg[i];
      f2 wz0 = wreg[i]*z0;
      pr0 += wy * z0;  pi0 += wy.yx * mk2(z0.x, -z0.y);  dd0 += wz0 * z0;
      pr1 += wy * z1;  pi1 += wy.yx * mk2(z1.x, -z1.y);  dd1 += (wreg[i]*z1) * z1;
      crr += wz0 * z1; cri += wz0.yx * mk2(z1.x, -z1.y);   // Rz = sum w z0 conj(z1)
    }
    float P0r = wred64(pr0.x+pr0.y), P0i = wred64(pi0.x+pi0.y), D0 = wred64(dd0.x+dd0.y);
    float P1r = wred64(pr1.x+pr1.y), P1i = wred64(pi1.x+pi1.y), D1 = wred64(dd1.x+dd1.y);
    float Rr  = wred64(crr.x+crr.y), Ri  = wred64(cri.x+cri.y);
    f2 v0 = (1.0f/fmaxf(D0, EPSF)) * mk2(P0r, P0i);
    f2 P1c = mk2(P1r, P1i) - cmul(v0, mk2(Rr, Ri));
    f2 v1 = (1.0f/fmaxf(D1, EPSF)) * P1c;
#pragma unroll
    for (int i = 0; i < 8; ++i) yreg[i] -= cmul(v0, z0c[i]) + cmul(v1, z1c[i]);
    if (lane < NS) sW[wv][lane] -= cmul(v0, sJ[0][lane]) + cmul(v1, sJ[1][lane]);
    else if (lane == NS)   sW[wv][NS+0] += v0;
    else if (lane == NS+1) sW[wv][NS+1] += v1;
  }
  __syncthreads();

  // ================= Binv -> inv (GJ on tid 0; overlaps type3) =============
  if (tid < 16) {
    int s = tid >> 2, d = tid & 3;
    f2 acc = sW[s][d];
    acc += cmul(sW[s][NS+0], sJ[0][d]);
    acc += cmul(sW[s][NS+1], sJ[1][d]);
    sB[s][d] = acc;
    sB[s][NS+d] = (s==d) ? mk2(1.f,0.f) : mk2(0.f,0.f);
  }
  __syncthreads();
  if (tid == 0) {
    for (int col = 0; col < NS; ++col) {
      int piv = col; float best = cmag2(sB[col][col]);
      for (int r = col+1; r < NS; ++r) { float m = cmag2(sB[r][col]); if (m > best) { best = m; piv = r; } }
      if (piv != col) for (int k = 0; k < 2*NS; ++k) { f2 t = sB[col][k]; sB[col][k] = sB[piv][k]; sB[piv][k] = t; }
      f2 ip = cinv(sB[col][col]);
      for (int k = 0; k < 2*NS; ++k) sB[col][k] = cmul(sB[col][k], ip);
      for (int r = 0; r < NS; ++r) if (r != col) {
        f2 fac = sB[r][col];
        for (int k = 0; k < 2*NS; ++k) sB[r][k] -= cmul(fac, sB[col][k]);
      }
    }
  }

  // ================= type3: sequential rounds (barrier-free; regs Y/w) =====
  {
#pragma unroll 1
    for (int src = 0; src < NC; ++src) {
      const f2* __restrict__ xrow = &sXp[src][0];
#pragma unroll
      for (int tap = 0; tap < NT; ++tap) {
        const int xoff = XPAD - (NDLY + tap) + lane;
        f2 xs[8];
        f2 nr2 = mk2(0.f,0.f), ni2 = mk2(0.f,0.f), dd2 = mk2(0.f,0.f);
#pragma unroll
        for (int i = 0; i < 8; ++i) {
          xs[i] = xrow[xoff + 64*i];
          f2 wy = wreg[i]*yreg[i];
          nr2 += wy * xs[i];
          ni2 += wy.yx * mk2(xs[i].x, -xs[i].y);
          dd2 += (wreg[i]*xs[i]) * xs[i];
        }
        float nr = wred64(nr2.x+nr2.y), ni = wred64(ni2.x+ni2.y), dd = wred64(dd2.x+dd2.y);
        f2 vc = (1.0f/fmaxf(dd, EPSF)) * mk2(nr, ni);
#pragma unroll
        for (int i = 0; i < 8; ++i) yreg[i] -= cmul(vc, xs[i]);
      }
    }
  }

  // ================= epilogue =================
  {
    const size_t yb = ((size_t)(b*NS + wv)*NFQ + f)*NFR;
    if (last) {
#pragma unroll
      for (int i = 0; i < 8; ++i) { int n = lane+64*i; if (n < NFR) outR[yb+n] = yreg[i].x; }
    } else {
#pragma unroll
      for (int i = 0; i < 8; ++i) { int n = lane+64*i; if (n < NFR) Yg[yb+n] = yreg[i]; }
    }
  }
  if (!last) {
    __syncthreads();   // sB (GJ), sW/sJ cross-wave reads below
    for (int k = 0; k < NBK; ++k) {
      const size_t zb = ((size_t)(b*NBK+k)*NFQ + f)*NFR;
      for (int n = tid; n < NFR; n += 256) Zg[zb+n] = sZ[k][n];
    }
    if (tid < NS*NC) Wg[((size_t)(b*NS + tid/NC)*NFQ + f)*NC + tid%NC] = sW[tid/NC][tid%NC];
    else if (tid < NS*NC + NBK*NS) { int t = tid - NS*NC; Jg[((size_t)(b*NBK + t/NS)*NFQ + f)*NS + t%NS] = sJ[t/NS][t%NS]; }
    else if (tid < NS*NC + NBK*NS + NS*NS) { int t = tid - NS*NC - NBK*NS; Ag[((size_t)(b*NS + t/NS)*NFQ + f)*NS + t%NS] = sB[t/NS][NS + t%NS]; }
  }
}

// ---------------------------------------------------------------------------
extern "C" void kernel_launch(void* const* d_in, const int* in_sizes, int n_in,
                              void* d_out, int out_size, void* d_ws, size_t ws_size,
                              hipStream_t stream)
{
  (void)in_sizes; (void)n_in; (void)out_size; (void)ws_size;
  const float* Xr = (const float*)d_in[0];
  const float* Xi = (const float*)d_in[1];
  float* outR = (float*)d_out;   // d_out = re(Y), float32, (2,4,320,500)

  char* ws = (char*)d_ws;
  size_t off = 0;
  f2* Yg = (f2*)(ws + off); off += (size_t)NB*NS*NFQ*NFR*sizeof(f2);   // 10,240,000
  f2* Zg = (f2*)(ws + off); off += (size_t)NB*NBK*NFQ*NFR*sizeof(f2);  //  5,120,000
  f2* Wg = (f2*)(ws + off); off += (size_t)NB*NS*NFQ*NC*sizeof(f2);    //    122,880
  f2* Jg = (f2*)(ws + off); off += (size_t)NB*NBK*NFQ*NS*sizeof(f2);   //     40,960
  f2* Ag = (f2*)(ws + off); off += (size_t)NB*NS*NFQ*NS*sizeof(f2);    //     81,920
  float* wacc = (float*)(ws + off); off += (size_t)NCH*NB*NS*NFR*sizeof(float); // 128,000

  k_init<<<NB*NFQ, 256, 0, stream>>>(Xr, Xi, Yg, Zg, Wg, Jg, Ag);
  for (int it = 0; it < 2; ++it) {
    k_wpart<<<NB*NS*NCH, 512, 0, stream>>>(Yg, wacc);
    k_iter<<<NB*NFQ, 256, 0, stream>>>(Xr, Xi, Yg, Zg, Wg, Jg, Ag, wacc, outR, it == 1);
  }
}